// Round 1
// 835.462 us; speedup vs baseline: 1.1730x; 1.1730x over previous
//
#include <hip/hip_runtime.h>

#define D_FEAT 64
#define SCAN_BLOCK 256
#define SCAN_ITEMS 16
#define SCAN_CHUNK (SCAN_BLOCK * SCAN_ITEMS)   // 4096 elements per scan block
#define SCANB_THREADS 1024                     // supports up to 1024 scan blocks (~4.2M rows)

typedef unsigned int u32;
typedef float f4 __attribute__((ext_vector_type(4)));

// ===================== TIER 1: fixed-capacity row buckets (no count/scan) ===========
// slots[row*cap + k] holds col | sign<<31 for the k-th edge of the row.
// Rows with degree > cap overflow into a small spill list applied atomically at the end.
// Degrees ~ Poisson(6): P(deg>16) ~ 1e-4 -> ~100 spilled edges out of 3M.

__global__ __launch_bounds__(256) void scatter_slot_kernel(
    const int* __restrict__ rows, const int* __restrict__ cols,
    const float* __restrict__ vals, u32* __restrict__ cnt,
    u32* __restrict__ slots, u32* __restrict__ spill,
    u32* __restrict__ spill_cnt, int nnz, int cap, u32 spill_cap) {
    int i4 = blockIdx.x * blockDim.x + threadIdx.x;
    long long base = (long long)i4 * 4;
    if (base >= nnz) return;

    int r0, r1, r2, r3, c0, c1, c2, c3;
    float v0, v1, v2, v3;
    if (base + 3 < nnz) {
        int4 rr = *(const int4*)(rows + base);
        int4 cc = *(const int4*)(cols + base);
        float4 vv = *(const float4*)(vals + base);
        r0 = rr.x; r1 = rr.y; r2 = rr.z; r3 = rr.w;
        c0 = cc.x; c1 = cc.y; c2 = cc.z; c3 = cc.w;
        v0 = vv.x; v1 = vv.y; v2 = vv.z; v3 = vv.w;
    } else {
        r0 = r1 = r2 = r3 = -1;
        c0 = c1 = c2 = c3 = 0;
        v0 = v1 = v2 = v3 = 0.f;
        if (base + 0 < nnz) { r0 = rows[base + 0]; c0 = cols[base + 0]; v0 = vals[base + 0]; }
        if (base + 1 < nnz) { r1 = rows[base + 1]; c1 = cols[base + 1]; v1 = vals[base + 1]; }
        if (base + 2 < nnz) { r2 = rows[base + 2]; c2 = cols[base + 2]; v2 = vals[base + 2]; }
    }

#define SCATTER_ONE(RK, CK, VK)                                                      \
    if (RK >= 0) {                                                                   \
        u32 entry = (u32)CK | ((VK < 0.f) ? 0x80000000u : 0u);                       \
        u32 slot = atomicAdd(&cnt[RK], 1u);                                          \
        if (slot < (u32)cap) {                                                       \
            slots[(size_t)RK * (size_t)cap + slot] = entry;                          \
        } else {                                                                     \
            u32 kk = atomicAdd(spill_cnt, 1u);                                       \
            if (kk < spill_cap) { spill[2 * kk] = (u32)RK; spill[2 * kk + 1] = entry; } \
        }                                                                            \
    }
    SCATTER_ONE(r0, c0, v0)
    SCATTER_ONE(r1, c1, v1)
    SCATTER_ONE(r2, c2, v2)
    SCATTER_ONE(r3, c3, v3)
#undef SCATTER_ONE
}

// One wave per output row. 4 groups of 16 lanes: group g owns edges g, g+4, g+8, g+12;
// each lane loads a float4 (dims 4s..4s+3). All <=4 loads hoisted before any FMA
// (max bytes in flight), then cross-group reduce via shfl_xor(16,32); lanes 0..15 store.
__global__ __launch_bounds__(256) void gather_slot_kernel(
    const f4* __restrict__ feat4, const u32* __restrict__ cnt,
    const u32* __restrict__ slots, f4* __restrict__ out4, int numV, int cap) {
    long long tid = (long long)blockIdx.x * blockDim.x + threadIdx.x;
    long long wid = tid >> 6;
    if (wid >= numV) return;
    int lane = (int)(tid & 63);
    int g = lane >> 4;
    int s = lane & 15;

    u32 n = cnt[wid];
    n = (u32)__builtin_amdgcn_readfirstlane((int)n);   // wave-uniform -> SGPR
    if (n > (u32)cap) n = (u32)cap;
    int ni = (int)n;

    int sl = (s < cap) ? s : (cap - 1);
    u32 ent = slots[wid * (long long)cap + sl];        // 64B line per row, broadcast

    u32 e0 = __shfl(ent, g);
    u32 e1 = __shfl(ent, g + 4);
    u32 e2 = __shfl(ent, g + 8);
    u32 e3 = __shfl(ent, g + 12);

    f4 f0 = {0.f, 0.f, 0.f, 0.f}, f1 = f0, f2 = f0, f3 = f0;
    if (g + 0 < ni)  f0 = feat4[(size_t)(e0 & 0x7fffffffu) * 16 + s];
    if (g + 4 < ni)  f1 = feat4[(size_t)(e1 & 0x7fffffffu) * 16 + s];
    if (g + 8 < ni)  f2 = feat4[(size_t)(e2 & 0x7fffffffu) * 16 + s];
    if (g + 12 < ni) f3 = feat4[(size_t)(e3 & 0x7fffffffu) * 16 + s];

    float s0 = (e0 & 0x80000000u) ? -1.f : 1.f;
    float s1 = (e1 & 0x80000000u) ? -1.f : 1.f;
    float s2 = (e2 & 0x80000000u) ? -1.f : 1.f;
    float s3 = (e3 & 0x80000000u) ? -1.f : 1.f;

    f4 acc = f0 * s0;
    acc += f1 * s1;
    acc += f2 * s2;
    acc += f3 * s3;

#pragma unroll
    for (int m = 16; m <= 32; m <<= 1) {
        acc.x += __shfl_xor(acc.x, m);
        acc.y += __shfl_xor(acc.y, m);
        acc.z += __shfl_xor(acc.z, m);
        acc.w += __shfl_xor(acc.w, m);
    }
    if (g == 0) __builtin_nontemporal_store(acc, &out4[wid * 16 + s]);
}

// Apply spilled edges (expected ~hundreds). One wave per entry, grid-stride.
__global__ __launch_bounds__(256) void spill_apply_kernel(
    const float* __restrict__ feat, const u32* __restrict__ spill,
    const u32* __restrict__ spill_cnt, float* __restrict__ out, u32 spill_cap) {
    u32 total = *spill_cnt;
    if (total > spill_cap) total = spill_cap;
    int lane = threadIdx.x & 63;
    u32 wid = (blockIdx.x * blockDim.x + threadIdx.x) >> 6;
    u32 nw = (gridDim.x * blockDim.x) >> 6;
    for (u32 i = wid; i < total; i += nw) {
        u32 r = spill[2 * i];
        u32 e = spill[2 * i + 1];
        float f = feat[(size_t)(e & 0x7fffffffu) * D_FEAT + lane];
        atomicAdd(&out[(size_t)r * D_FEAT + lane], (e & 0x80000000u) ? -f : f);
    }
}

// ===================== TIER 2: CSR build (count/scan/scatter) — verified path =======

__global__ __launch_bounds__(256) void count_kernel(const int* __restrict__ rows,
                                                    u32* __restrict__ cnt, int nnz) {
    int e = blockIdx.x * blockDim.x + threadIdx.x;
    if (e < nnz) atomicAdd(&cnt[rows[e]], 1u);
}

__global__ __launch_bounds__(SCAN_BLOCK) void scanA_kernel(const u32* __restrict__ cnt,
                                                           u32* __restrict__ bsums, int n) {
    int t = threadIdx.x, b = blockIdx.x;
    int i0 = b * SCAN_CHUNK + t * SCAN_ITEMS;
    u32 s = 0;
#pragma unroll
    for (int k = 0; k < SCAN_ITEMS; ++k) {
        int i = i0 + k;
        if (i < n) s += cnt[i];
    }
    __shared__ u32 red[SCAN_BLOCK];
    red[t] = s;
    __syncthreads();
    for (int d = SCAN_BLOCK / 2; d > 0; d >>= 1) {
        if (t < d) red[t] += red[t + d];
        __syncthreads();
    }
    if (t == 0) bsums[b] = red[0];
}

__global__ __launch_bounds__(SCANB_THREADS) void scanB_kernel(u32* __restrict__ bsums, int nb,
                                                              u32* __restrict__ off, int numV,
                                                              u32 nnz) {
    int t = threadIdx.x;
    __shared__ u32 tmp[SCANB_THREADS];
    u32 v = (t < nb) ? bsums[t] : 0u;
    tmp[t] = v;
    __syncthreads();
    for (int d = 1; d < SCANB_THREADS; d <<= 1) {
        u32 x = (t >= d) ? tmp[t - d] : 0u;
        __syncthreads();
        tmp[t] += x;
        __syncthreads();
    }
    if (t < nb) bsums[t] = tmp[t] - v;   // exclusive
    if (t == 0) off[numV] = nnz;
}

__global__ __launch_bounds__(SCAN_BLOCK) void scanC_kernel(const u32* __restrict__ cnt,
                                                           const u32* __restrict__ bsums,
                                                           u32* __restrict__ off,
                                                           u32* __restrict__ cursor, int n) {
    int t = threadIdx.x, b = blockIdx.x;
    int i0 = b * SCAN_CHUNK + t * SCAN_ITEMS;
    u32 s = 0;
#pragma unroll
    for (int k = 0; k < SCAN_ITEMS; ++k) {
        int i = i0 + k;
        if (i < n) s += cnt[i];
    }
    __shared__ u32 tmp[SCAN_BLOCK];
    tmp[t] = s;
    __syncthreads();
    for (int d = 1; d < SCAN_BLOCK; d <<= 1) {
        u32 x = (t >= d) ? tmp[t - d] : 0u;
        __syncthreads();
        tmp[t] += x;
        __syncthreads();
    }
    u32 run = bsums[b] + (tmp[t] - s);
    for (int k = 0; k < SCAN_ITEMS; ++k) {
        int i = i0 + k;
        if (i < n) {
            off[i] = run;
            cursor[i] = run;
            run += cnt[i];
        }
    }
}

__global__ __launch_bounds__(256) void scatter_kernel(const int* __restrict__ rows,
                                                      const int* __restrict__ cols,
                                                      const float* __restrict__ vals,
                                                      u32* __restrict__ cursor,
                                                      u32* __restrict__ packed, int nnz) {
    int e = blockIdx.x * blockDim.x + threadIdx.x;
    if (e >= nnz) return;
    int r = rows[e];
    u32 pos = atomicAdd(&cursor[r], 1u);
    u32 entry = (u32)cols[e] | (vals[e] < 0.f ? 0x80000000u : 0u);
    packed[pos] = entry;
}

__global__ __launch_bounds__(256) void gather_kernel(const float* __restrict__ feat,
                                                     const u32* __restrict__ off,
                                                     const u32* __restrict__ packed,
                                                     float* __restrict__ out, int numV) {
    long long tid = (long long)blockIdx.x * blockDim.x + threadIdx.x;
    long long wid = tid >> 6;
    int lane = (int)(tid & 63);
    if (wid >= numV) return;

    u32 s = off[wid];
    u32 e = off[wid + 1];
    float acc = 0.f;

    for (u32 base = s; base < e; base += 64) {
        int cnt = (int)min(64u, e - base);
        u32 ent = (lane < cnt) ? packed[base + lane] : 0u;
        for (int j0 = 0; j0 < cnt; j0 += 4) {
            float f[4], sg[4];
#pragma unroll
            for (int k = 0; k < 4; ++k) {
                int j = j0 + k;
                u32 ej = __shfl(ent, j);
                long long c = (long long)(ej & 0x7fffffffu);
                sg[k] = (ej >> 31) ? -1.f : 1.f;
                f[k] = (j < cnt) ? feat[c * D_FEAT + lane] : 0.f;
            }
#pragma unroll
            for (int k = 0; k < 4; ++k) acc = fmaf(sg[k], f[k], acc);
        }
    }
    out[wid * D_FEAT + lane] = acc;
}

// ===================== TIER 3: atomic fallback ======================================
__global__ __launch_bounds__(256) void atomic_fallback_kernel(
    const float* __restrict__ feat, const float* __restrict__ vals,
    const int* __restrict__ rows, const int* __restrict__ cols,
    float* __restrict__ out, long long nnz) {
    long long tid = (long long)blockIdx.x * blockDim.x + threadIdx.x;
    long long e = tid >> 6;
    int d = (int)(tid & 63);
    if (e >= nnz) return;
    float f = feat[(long long)cols[e] * D_FEAT + d];
    atomicAdd(out + (long long)rows[e] * D_FEAT + d, vals[e] * f);
}

extern "C" void kernel_launch(void* const* d_in, const int* in_sizes, int n_in,
                              void* d_out, int out_size, void* d_ws, size_t ws_size,
                              hipStream_t stream) {
    const float* feat = (const float*)d_in[0];  // [NUM_E, 64] fp32
    const float* vals = (const float*)d_in[1];  // [NNZ] fp32 (+/-1)
    const int*   rows = (const int*)d_in[2];    // [NNZ] int32
    const int*   cols = (const int*)d_in[3];    // [NNZ] int32
    float*       out  = (float*)d_out;          // [NUM_V, 64] fp32

    int nnz  = in_sizes[1];
    int numV = out_size / D_FEAT;

    // ---------------- TIER 1: slot buckets ------------------------------------------
    {
        // ws layout (u32): [cnt: numV][spill_cnt: 1 + pad][slots: numV*cap][spill: 2*spcap]
        size_t metaU = (((size_t)numV + 16) + 15) & ~(size_t)15;
        int cap = 0; u32 spcap = 0;
        {
            size_t need16 = (metaU + (size_t)numV * 16 + 2 * (size_t)(1u << 20)) * sizeof(u32);
            size_t need12 = (metaU + (size_t)numV * 12 + 2 * (size_t)(1u << 18)) * sizeof(u32);
            if (ws_size >= need16)      { cap = 16; spcap = 1u << 20; }
            else if (ws_size >= need12) { cap = 12; spcap = 1u << 18; }
        }
        if (cap) {
            u32* ws        = (u32*)d_ws;
            u32* cnt       = ws;
            u32* spill_cnt = ws + numV;
            u32* slots     = ws + metaU;
            u32* spill     = slots + (size_t)numV * cap;

            hipMemsetAsync(cnt, 0, (size_t)(numV + 16) * sizeof(u32), stream);

            int nth4 = (nnz + 3) / 4;
            int nb4  = (nth4 + 255) / 256;
            scatter_slot_kernel<<<nb4, 256, 0, stream>>>(rows, cols, vals, cnt, slots,
                                                         spill, spill_cnt, nnz, cap, spcap);

            long long gthreads = (long long)numV * 64;
            int gblocks = (int)((gthreads + 255) / 256);
            gather_slot_kernel<<<gblocks, 256, 0, stream>>>((const f4*)feat, cnt, slots,
                                                            (f4*)out, numV, cap);
            spill_apply_kernel<<<64, 256, 0, stream>>>(feat, spill, spill_cnt, out, spcap);
            return;
        }
    }

    // ---------------- TIER 2: CSR build (previous verified path) --------------------
    int nScanBlocks = (numV + SCAN_CHUNK - 1) / SCAN_CHUNK;
    size_t need = ((size_t)(numV + 1) + numV + numV + SCANB_THREADS + nnz) * sizeof(u32);

    if (ws_size < need || nScanBlocks > SCANB_THREADS) {
        hipMemsetAsync(d_out, 0, (size_t)out_size * sizeof(float), stream);
        long long total = (long long)nnz * D_FEAT;
        long long nblk = (total + 255) / 256;
        atomic_fallback_kernel<<<(dim3)((unsigned)nblk), 256, 0, stream>>>(
            feat, vals, rows, cols, out, nnz);
        return;
    }

    u32* ws     = (u32*)d_ws;
    u32* off    = ws;
    u32* cursor = off + (numV + 1);
    u32* cnt    = cursor + numV;
    u32* bsums  = cnt + numV;
    u32* packed = bsums + SCANB_THREADS;

    hipMemsetAsync(cnt, 0, (size_t)numV * sizeof(u32), stream);

    int nb256 = (nnz + 255) / 256;
    count_kernel<<<nb256, 256, 0, stream>>>(rows, cnt, nnz);
    scanA_kernel<<<nScanBlocks, SCAN_BLOCK, 0, stream>>>(cnt, bsums, numV);
    scanB_kernel<<<1, SCANB_THREADS, 0, stream>>>(bsums, nScanBlocks, off, numV, (u32)nnz);
    scanC_kernel<<<nScanBlocks, SCAN_BLOCK, 0, stream>>>(cnt, bsums, off, cursor, numV);
    scatter_kernel<<<nb256, 256, 0, stream>>>(rows, cols, vals, cursor, packed, nnz);

    long long gthreads = (long long)numV * 64;
    long long gblocks  = (gthreads + 255) / 256;
    gather_kernel<<<(dim3)((unsigned)gblocks), 256, 0, stream>>>(feat, off, packed, out, numV);
}

// Round 2
// 752.142 us; speedup vs baseline: 1.3029x; 1.1108x over previous
//
#include <hip/hip_runtime.h>

#define D_FEAT 64
#define SCAN_BLOCK 256
#define SCAN_ITEMS 16
#define SCAN_CHUNK (SCAN_BLOCK * SCAN_ITEMS)   // 4096 elements per scan block
#define SCANB_THREADS 1024                     // supports up to 1024 scan blocks (~4.2M rows)

#define EMPTY_SLOT 0xFFFFFFFFu
#define ROW_CAP 16                              // 16 u32 slots = one 64B line per row

typedef unsigned int u32;
typedef float f4 __attribute__((ext_vector_type(4)));

// ===================== TIER 1: CAS-claim row buckets ================================
// slots[row*16 + k] holds col | sign<<31. Init to EMPTY (0xFFFFFFFF; impossible entry
// since col < 2^31). Each edge claims a slot via atomicCAS with linear probing inside
// the row's own 64B line: the CAS *is* the store (no cnt array, no dependent store).
// Rows with degree > 16 overflow into a small spill list applied atomically at the end.

__device__ __forceinline__ void slow_claim(u32* __restrict__ line, u32 entry, u32 h,
                                           u32 r, u32* __restrict__ spill,
                                           u32* __restrict__ spill_cnt, u32 spill_cap) {
    for (u32 p = 1; p < ROW_CAP; ++p) {
        u32 old = atomicCAS(line + ((h + p) & (ROW_CAP - 1)), EMPTY_SLOT, entry);
        if (old == EMPTY_SLOT) return;
    }
    u32 kk = atomicAdd(spill_cnt, 1u);
    if (kk < spill_cap) { spill[2 * kk] = r; spill[2 * kk + 1] = entry; }
}

__global__ __launch_bounds__(256) void scatter_cas_kernel(
    const int* __restrict__ rows, const int* __restrict__ cols,
    const float* __restrict__ vals, u32* __restrict__ slots,
    u32* __restrict__ spill, u32* __restrict__ spill_cnt, int nnz, u32 spill_cap) {
    long long i4 = (long long)blockIdx.x * blockDim.x + threadIdx.x;
    long long base = i4 * 4;
    if (base >= nnz) return;

    if (base + 3 < nnz) {
        int4 rr = *(const int4*)(rows + base);
        int4 cc = *(const int4*)(cols + base);
        float4 vv = *(const float4*)(vals + base);

        u32 e0 = (u32)cc.x | (vv.x < 0.f ? 0x80000000u : 0u);
        u32 e1 = (u32)cc.y | (vv.y < 0.f ? 0x80000000u : 0u);
        u32 e2 = (u32)cc.z | (vv.z < 0.f ? 0x80000000u : 0u);
        u32 e3 = (u32)cc.w | (vv.w < 0.f ? 0x80000000u : 0u);

        u32* L0 = slots + (size_t)rr.x * ROW_CAP;
        u32* L1 = slots + (size_t)rr.y * ROW_CAP;
        u32* L2 = slots + (size_t)rr.z * ROW_CAP;
        u32* L3 = slots + (size_t)rr.w * ROW_CAP;

        u32 h0 = (u32)(base + 0) & (ROW_CAP - 1);
        u32 h1 = (u32)(base + 1) & (ROW_CAP - 1);
        u32 h2 = (u32)(base + 2) & (ROW_CAP - 1);
        u32 h3 = (u32)(base + 3) & (ROW_CAP - 1);

        // 4 independent first-probe CAS in flight; slow path only on collision (~25%)
        u32 o0 = atomicCAS(L0 + h0, EMPTY_SLOT, e0);
        u32 o1 = atomicCAS(L1 + h1, EMPTY_SLOT, e1);
        u32 o2 = atomicCAS(L2 + h2, EMPTY_SLOT, e2);
        u32 o3 = atomicCAS(L3 + h3, EMPTY_SLOT, e3);

        if (o0 != EMPTY_SLOT) slow_claim(L0, e0, h0, (u32)rr.x, spill, spill_cnt, spill_cap);
        if (o1 != EMPTY_SLOT) slow_claim(L1, e1, h1, (u32)rr.y, spill, spill_cnt, spill_cap);
        if (o2 != EMPTY_SLOT) slow_claim(L2, e2, h2, (u32)rr.z, spill, spill_cnt, spill_cap);
        if (o3 != EMPTY_SLOT) slow_claim(L3, e3, h3, (u32)rr.w, spill, spill_cnt, spill_cap);
    } else {
        for (int k = 0; k < 4; ++k) {
            long long e = base + k;
            if (e >= nnz) break;
            int r = rows[e];
            u32 entry = (u32)cols[e] | (vals[e] < 0.f ? 0x80000000u : 0u);
            u32* line = slots + (size_t)r * ROW_CAP;
            u32 h = (u32)e & (ROW_CAP - 1);
            u32 old = atomicCAS(line + h, EMPTY_SLOT, entry);
            if (old != EMPTY_SLOT) slow_claim(line, entry, h, (u32)r, spill, spill_cnt, spill_cap);
        }
    }
}

// Two rows per wave. Lanes 0-31 hold row0's 16-slot line (dup x2), lanes 32-63 row1's.
// Group g (16 lanes) handles slots {g, g+4, g+8, g+12} of BOTH rows: 8 independent
// predicated float4 loads hoisted before any FMA (8KB/wave in flight), then two
// butterfly reductions; groups 0 and 1 do the two coalesced nontemporal 256B stores.
__global__ __launch_bounds__(256) void gather_cas_kernel(
    const f4* __restrict__ feat4, const u32* __restrict__ slots,
    f4* __restrict__ out4, int numV) {
    long long tid = (long long)blockIdx.x * blockDim.x + threadIdx.x;
    long long pair = tid >> 6;
    long long r0 = pair * 2;
    if (r0 >= numV) return;
    long long r1 = r0 + 1;
    bool have1 = (r1 < numV);
    int lane = (int)(tid & 63);
    int g = lane >> 4;
    int s = lane & 15;

    long long rme = (g < 2) ? r0 : (have1 ? r1 : r0);
    u32 ent = slots[rme * ROW_CAP + s];

    u32 a0 = __shfl(ent, g);
    u32 a1 = __shfl(ent, g + 4);
    u32 a2 = __shfl(ent, g + 8);
    u32 a3 = __shfl(ent, g + 12);
    u32 b0 = __shfl(ent, 32 + g);
    u32 b1 = __shfl(ent, 36 + g);
    u32 b2 = __shfl(ent, 40 + g);
    u32 b3 = __shfl(ent, 44 + g);

    const f4 z = {0.f, 0.f, 0.f, 0.f};
    f4 f0 = z, f1 = z, f2 = z, f3 = z, g0 = z, g1 = z, g2 = z, g3 = z;
    if (a0 != EMPTY_SLOT) f0 = feat4[(size_t)(a0 & 0x7fffffffu) * 16 + s];
    if (a1 != EMPTY_SLOT) f1 = feat4[(size_t)(a1 & 0x7fffffffu) * 16 + s];
    if (a2 != EMPTY_SLOT) f2 = feat4[(size_t)(a2 & 0x7fffffffu) * 16 + s];
    if (a3 != EMPTY_SLOT) f3 = feat4[(size_t)(a3 & 0x7fffffffu) * 16 + s];
    if (have1) {
        if (b0 != EMPTY_SLOT) g0 = feat4[(size_t)(b0 & 0x7fffffffu) * 16 + s];
        if (b1 != EMPTY_SLOT) g1 = feat4[(size_t)(b1 & 0x7fffffffu) * 16 + s];
        if (b2 != EMPTY_SLOT) g2 = feat4[(size_t)(b2 & 0x7fffffffu) * 16 + s];
        if (b3 != EMPTY_SLOT) g3 = feat4[(size_t)(b3 & 0x7fffffffu) * 16 + s];
    }

    float s0 = (a0 >> 31) ? 1.f : -1.f;   // EMPTY has sign bit set but f=0, harmless
    float s1 = (a1 >> 31) ? 1.f : -1.f;
    float s2 = (a2 >> 31) ? 1.f : -1.f;
    float s3 = (a3 >> 31) ? 1.f : -1.f;
    // note: entry sign bit 1 means negative value -> multiply by -1
    s0 = -s0; s1 = -s1; s2 = -s2; s3 = -s3;
    f4 acc0 = f0 * s0 + f1 * s1 + f2 * s2 + f3 * s3;

    float t0 = (b0 >> 31) ? -1.f : 1.f;
    float t1 = (b1 >> 31) ? -1.f : 1.f;
    float t2 = (b2 >> 31) ? -1.f : 1.f;
    float t3 = (b3 >> 31) ? -1.f : 1.f;
    f4 acc1 = g0 * t0 + g1 * t1 + g2 * t2 + g3 * t3;

#pragma unroll
    for (int m = 16; m <= 32; m <<= 1) {
        acc0.x += __shfl_xor(acc0.x, m);
        acc0.y += __shfl_xor(acc0.y, m);
        acc0.z += __shfl_xor(acc0.z, m);
        acc0.w += __shfl_xor(acc0.w, m);
        acc1.x += __shfl_xor(acc1.x, m);
        acc1.y += __shfl_xor(acc1.y, m);
        acc1.z += __shfl_xor(acc1.z, m);
        acc1.w += __shfl_xor(acc1.w, m);
    }
    if (g == 0) __builtin_nontemporal_store(acc0, &out4[r0 * 16 + s]);
    if (g == 1 && have1) __builtin_nontemporal_store(acc1, &out4[r1 * 16 + s]);
}

// Apply spilled edges (expected ~tens). One wave per entry, grid-stride.
__global__ __launch_bounds__(256) void spill_apply_kernel(
    const float* __restrict__ feat, const u32* __restrict__ spill,
    const u32* __restrict__ spill_cnt, float* __restrict__ out, u32 spill_cap) {
    u32 total = *spill_cnt;
    if (total > spill_cap) total = spill_cap;
    int lane = threadIdx.x & 63;
    u32 wid = (blockIdx.x * blockDim.x + threadIdx.x) >> 6;
    u32 nw = (gridDim.x * blockDim.x) >> 6;
    for (u32 i = wid; i < total; i += nw) {
        u32 r = spill[2 * i];
        u32 e = spill[2 * i + 1];
        float f = feat[(size_t)(e & 0x7fffffffu) * D_FEAT + lane];
        atomicAdd(&out[(size_t)r * D_FEAT + lane], (e & 0x80000000u) ? -f : f);
    }
}

// ===================== TIER 2: CSR build (count/scan/scatter) — verified path =======

__global__ __launch_bounds__(256) void count_kernel(const int* __restrict__ rows,
                                                    u32* __restrict__ cnt, int nnz) {
    int e = blockIdx.x * blockDim.x + threadIdx.x;
    if (e < nnz) atomicAdd(&cnt[rows[e]], 1u);
}

__global__ __launch_bounds__(SCAN_BLOCK) void scanA_kernel(const u32* __restrict__ cnt,
                                                           u32* __restrict__ bsums, int n) {
    int t = threadIdx.x, b = blockIdx.x;
    int i0 = b * SCAN_CHUNK + t * SCAN_ITEMS;
    u32 s = 0;
#pragma unroll
    for (int k = 0; k < SCAN_ITEMS; ++k) {
        int i = i0 + k;
        if (i < n) s += cnt[i];
    }
    __shared__ u32 red[SCAN_BLOCK];
    red[t] = s;
    __syncthreads();
    for (int d = SCAN_BLOCK / 2; d > 0; d >>= 1) {
        if (t < d) red[t] += red[t + d];
        __syncthreads();
    }
    if (t == 0) bsums[b] = red[0];
}

__global__ __launch_bounds__(SCANB_THREADS) void scanB_kernel(u32* __restrict__ bsums, int nb,
                                                              u32* __restrict__ off, int numV,
                                                              u32 nnz) {
    int t = threadIdx.x;
    __shared__ u32 tmp[SCANB_THREADS];
    u32 v = (t < nb) ? bsums[t] : 0u;
    tmp[t] = v;
    __syncthreads();
    for (int d = 1; d < SCANB_THREADS; d <<= 1) {
        u32 x = (t >= d) ? tmp[t - d] : 0u;
        __syncthreads();
        tmp[t] += x;
        __syncthreads();
    }
    if (t < nb) bsums[t] = tmp[t] - v;   // exclusive
    if (t == 0) off[numV] = nnz;
}

__global__ __launch_bounds__(SCAN_BLOCK) void scanC_kernel(const u32* __restrict__ cnt,
                                                           const u32* __restrict__ bsums,
                                                           u32* __restrict__ off,
                                                           u32* __restrict__ cursor, int n) {
    int t = threadIdx.x, b = blockIdx.x;
    int i0 = b * SCAN_CHUNK + t * SCAN_ITEMS;
    u32 s = 0;
#pragma unroll
    for (int k = 0; k < SCAN_ITEMS; ++k) {
        int i = i0 + k;
        if (i < n) s += cnt[i];
    }
    __shared__ u32 tmp[SCAN_BLOCK];
    tmp[t] = s;
    __syncthreads();
    for (int d = 1; d < SCAN_BLOCK; d <<= 1) {
        u32 x = (t >= d) ? tmp[t - d] : 0u;
        __syncthreads();
        tmp[t] += x;
        __syncthreads();
    }
    u32 run = bsums[b] + (tmp[t] - s);
    for (int k = 0; k < SCAN_ITEMS; ++k) {
        int i = i0 + k;
        if (i < n) {
            off[i] = run;
            cursor[i] = run;
            run += cnt[i];
        }
    }
}

__global__ __launch_bounds__(256) void scatter_kernel(const int* __restrict__ rows,
                                                      const int* __restrict__ cols,
                                                      const float* __restrict__ vals,
                                                      u32* __restrict__ cursor,
                                                      u32* __restrict__ packed, int nnz) {
    int e = blockIdx.x * blockDim.x + threadIdx.x;
    if (e >= nnz) return;
    int r = rows[e];
    u32 pos = atomicAdd(&cursor[r], 1u);
    u32 entry = (u32)cols[e] | (vals[e] < 0.f ? 0x80000000u : 0u);
    packed[pos] = entry;
}

__global__ __launch_bounds__(256) void gather_kernel(const float* __restrict__ feat,
                                                     const u32* __restrict__ off,
                                                     const u32* __restrict__ packed,
                                                     float* __restrict__ out, int numV) {
    long long tid = (long long)blockIdx.x * blockDim.x + threadIdx.x;
    long long wid = tid >> 6;
    int lane = (int)(tid & 63);
    if (wid >= numV) return;

    u32 s = off[wid];
    u32 e = off[wid + 1];
    float acc = 0.f;

    for (u32 base = s; base < e; base += 64) {
        int cnt = (int)min(64u, e - base);
        u32 ent = (lane < cnt) ? packed[base + lane] : 0u;
        for (int j0 = 0; j0 < cnt; j0 += 4) {
            float f[4], sg[4];
#pragma unroll
            for (int k = 0; k < 4; ++k) {
                int j = j0 + k;
                u32 ej = __shfl(ent, j);
                long long c = (long long)(ej & 0x7fffffffu);
                sg[k] = (ej >> 31) ? -1.f : 1.f;
                f[k] = (j < cnt) ? feat[c * D_FEAT + lane] : 0.f;
            }
#pragma unroll
            for (int k = 0; k < 4; ++k) acc = fmaf(sg[k], f[k], acc);
        }
    }
    out[wid * D_FEAT + lane] = acc;
}

// ===================== TIER 3: atomic fallback ======================================
__global__ __launch_bounds__(256) void atomic_fallback_kernel(
    const float* __restrict__ feat, const float* __restrict__ vals,
    const int* __restrict__ rows, const int* __restrict__ cols,
    float* __restrict__ out, long long nnz) {
    long long tid = (long long)blockIdx.x * blockDim.x + threadIdx.x;
    long long e = tid >> 6;
    int d = (int)(tid & 63);
    if (e >= nnz) return;
    float f = feat[(long long)cols[e] * D_FEAT + d];
    atomicAdd(out + (long long)rows[e] * D_FEAT + d, vals[e] * f);
}

extern "C" void kernel_launch(void* const* d_in, const int* in_sizes, int n_in,
                              void* d_out, int out_size, void* d_ws, size_t ws_size,
                              hipStream_t stream) {
    const float* feat = (const float*)d_in[0];  // [NUM_E, 64] fp32
    const float* vals = (const float*)d_in[1];  // [NNZ] fp32 (+/-1)
    const int*   rows = (const int*)d_in[2];    // [NNZ] int32
    const int*   cols = (const int*)d_in[3];    // [NNZ] int32
    float*       out  = (float*)d_out;          // [NUM_V, 64] fp32

    int nnz  = in_sizes[1];
    int numV = out_size / D_FEAT;

    // ---------------- TIER 1: CAS-claim slot buckets --------------------------------
    {
        // ws layout (u32): [spill_cnt + pad: 16][slots: numV*16][spill: 2*spcap]
        const u32 spcap = 1u << 20;
        size_t needT1 = (16 + (size_t)numV * ROW_CAP + 2 * (size_t)spcap) * sizeof(u32);
        if (ws_size >= needT1) {
            u32* ws        = (u32*)d_ws;
            u32* spill_cnt = ws;
            u32* slots     = ws + 16;
            u32* spill     = slots + (size_t)numV * ROW_CAP;

            hipMemsetAsync(spill_cnt, 0, 16 * sizeof(u32), stream);
            hipMemsetAsync(slots, 0xFF, (size_t)numV * ROW_CAP * sizeof(u32), stream);

            long long nth4 = ((long long)nnz + 3) / 4;
            int nb4 = (int)((nth4 + 255) / 256);
            scatter_cas_kernel<<<nb4, 256, 0, stream>>>(rows, cols, vals, slots,
                                                        spill, spill_cnt, nnz, spcap);

            long long pairs = ((long long)numV + 1) / 2;
            long long gthreads = pairs * 64;
            int gblocks = (int)((gthreads + 255) / 256);
            gather_cas_kernel<<<gblocks, 256, 0, stream>>>((const f4*)feat, slots,
                                                           (f4*)out, numV);
            spill_apply_kernel<<<64, 256, 0, stream>>>(feat, spill, spill_cnt, out, spcap);
            return;
        }
    }

    // ---------------- TIER 2: CSR build (previous verified path) --------------------
    int nScanBlocks = (numV + SCAN_CHUNK - 1) / SCAN_CHUNK;
    size_t need = ((size_t)(numV + 1) + numV + numV + SCANB_THREADS + nnz) * sizeof(u32);

    if (ws_size < need || nScanBlocks > SCANB_THREADS) {
        hipMemsetAsync(d_out, 0, (size_t)out_size * sizeof(float), stream);
        long long total = (long long)nnz * D_FEAT;
        long long nblk = (total + 255) / 256;
        atomic_fallback_kernel<<<(dim3)((unsigned)nblk), 256, 0, stream>>>(
            feat, vals, rows, cols, out, nnz);
        return;
    }

    u32* ws     = (u32*)d_ws;
    u32* off    = ws;
    u32* cursor = off + (numV + 1);
    u32* cnt    = cursor + numV;
    u32* bsums  = cnt + numV;
    u32* packed = bsums + SCANB_THREADS;

    hipMemsetAsync(cnt, 0, (size_t)numV * sizeof(u32), stream);

    int nb256 = (nnz + 255) / 256;
    count_kernel<<<nb256, 256, 0, stream>>>(rows, cnt, nnz);
    scanA_kernel<<<nScanBlocks, SCAN_BLOCK, 0, stream>>>(cnt, bsums, numV);
    scanB_kernel<<<1, SCANB_THREADS, 0, stream>>>(bsums, nScanBlocks, off, numV, (u32)nnz);
    scanC_kernel<<<nScanBlocks, SCAN_BLOCK, 0, stream>>>(cnt, bsums, off, cursor, numV);
    scatter_kernel<<<nb256, 256, 0, stream>>>(rows, cols, vals, cursor, packed, nnz);

    long long gthreads = (long long)numV * 64;
    long long gblocks  = (gthreads + 255) / 256;
    gather_kernel<<<(dim3)((unsigned)gblocks), 256, 0, stream>>>(feat, off, packed, out, numV);
}